// Round 12
// baseline (6190.242 us; speedup 1.0000x reference)
//
#include <hip/hip_runtime.h>
#include <stdint.h>
#include <math.h>

#define JAX_PARTITIONABLE 1

#define B_ 512
#define SEQ_ 50
#define H_ 256
#define H2_ 128
#define T_ 60
#define S_ 6
#define EMB_ 16
#define NL_ 2
#define TG_ 768     // 3*H
#define CAT_ 4096   // G*G
#define GUMBEL_N 629145600u  // (S-1)*T*B*CAT
#define NOISE_N 7864320u     // T*B*H

typedef float f32x2 __attribute__((ext_vector_type(2)));

// packed fp32 FMA, h broadcast via op_sel on src1 (bit-exact IEEE f32 FMA)
#define PKFMA_LO(acc, w, h) \
  asm("v_pk_fma_f32 %0, %1, %2, %0 op_sel:[0,0,0] op_sel_hi:[1,0,1]" : "+v"(acc) : "v"(w), "v"(h))
#define PKFMA_HI(acc, w, h) \
  asm("v_pk_fma_f32 %0, %1, %2, %0 op_sel:[0,1,0] op_sel_hi:[1,1,1]" : "+v"(acc) : "v"(w), "v"(h))

__host__ __device__ inline uint32_t rotl32(uint32_t x, int r) {
#if defined(__HIP_DEVICE_COMPILE__)
  return __builtin_amdgcn_alignbit(x, x, 32 - r);
#else
  return (x << r) | (x >> (32 - r));
#endif
}

// ---------------- Threefry-2x32 (20 rounds), matches jax._src.prng ----------------
__host__ __device__ inline void tf2x32(uint32_t k0, uint32_t k1, uint32_t x0, uint32_t x1,
                                       uint32_t& o0, uint32_t& o1) {
  uint32_t ks2 = k0 ^ k1 ^ 0x1BD11BDAu;
  x0 += k0; x1 += k1;
#define TFR(r) do { x0 += x1; x1 = rotl32(x1, r); x1 ^= x0; } while (0)
  TFR(13); TFR(15); TFR(26); TFR(6);
  x0 += k1; x1 += ks2 + 1u;
  TFR(17); TFR(29); TFR(16); TFR(24);
  x0 += ks2; x1 += k0 + 2u;
  TFR(13); TFR(15); TFR(26); TFR(6);
  x0 += k0; x1 += k1 + 3u;
  TFR(17); TFR(29); TFR(16); TFR(24);
  x0 += k1; x1 += ks2 + 4u;
  TFR(13); TFR(15); TFR(26); TFR(6);
  x0 += ks2; x1 += k0 + 5u;
#undef TFR
  o0 = x0; o1 = x1;
}

__device__ inline uint32_t jax_bits(uint32_t k0, uint32_t k1, uint32_t i, uint32_t n) {
#if JAX_PARTITIONABLE
  (void)n;
  uint32_t a, b;
  tf2x32(k0, k1, 0u, i, a, b);
  return a ^ b;
#else
  uint32_t half = n >> 1;
  uint32_t lo = (i < half) ? i : (i - half);
  uint32_t a, b;
  tf2x32(k0, k1, lo, lo + half, a, b);
  return (i < half) ? a : b;
#endif
}

__device__ inline float bits_to_f01(uint32_t bits) {
  return __uint_as_float((bits >> 9) | 0x3f800000u) - 1.0f;
}

// erf_inv, CHLO/Giles f32 polynomial; w from double log
__device__ inline float erfinv_f(float x) {
  double xd = (double)x;
  float w = (float)(-log((1.0 - xd) * (1.0 + xd)));
  float p;
  if (w < 5.0f) {
    w = __fadd_rn(w, -2.5f);
    p = 2.81022636e-08f;
    p = __fadd_rn(3.43273939e-07f, __fmul_rn(p, w));
    p = __fadd_rn(-3.5233877e-06f, __fmul_rn(p, w));
    p = __fadd_rn(-4.39150654e-06f, __fmul_rn(p, w));
    p = __fadd_rn(0.00021858087f, __fmul_rn(p, w));
    p = __fadd_rn(-0.00125372503f, __fmul_rn(p, w));
    p = __fadd_rn(-0.00417768164f, __fmul_rn(p, w));
    p = __fadd_rn(0.246640727f, __fmul_rn(p, w));
    p = __fadd_rn(1.50140941f, __fmul_rn(p, w));
  } else {
    w = __fadd_rn(__fsqrt_rn(w), -3.0f);
    p = -0.000200214257f;
    p = __fadd_rn(0.000100950558f, __fmul_rn(p, w));
    p = __fadd_rn(0.00134934322f, __fmul_rn(p, w));
    p = __fadd_rn(-0.00367342844f, __fmul_rn(p, w));
    p = __fadd_rn(0.00573950773f, __fmul_rn(p, w));
    p = __fadd_rn(-0.0076224613f, __fmul_rn(p, w));
    p = __fadd_rn(0.00943887047f, __fmul_rn(p, w));
    p = __fadd_rn(1.00167406f, __fmul_rn(p, w));
    p = __fadd_rn(2.83297682f, __fmul_rn(p, w));
  }
  return __fmul_rn(p, x);
}

__device__ inline uint32_t orderkey(float s) {
  uint32_t sb = __float_as_uint(s);
  return (sb & 0x80000000u) ? ~sb : (sb | 0x80000000u);
}

// ---------------- init ----------------
// ip: [0..511] etype, [512..1023] eidx, [1024..1535] order,
// tbl16 = ip+1536 (16-row tiles), tbl32 = ip+1664 (32-row tiles)
__global__ __launch_bounds__(512) void k_init(const float* __restrict__ hist,
                                              float* __restrict__ x0buf, int* __restrict__ ip) {
  int b = threadIdx.x;
  if (b < B_) {
    float tv = hist[b * 4800 + 5];
    int et = (int)tv;
    et = et < 0 ? 0 : (et > 9 ? 9 : et);
    const int mp[10] = {0, 1, 4, 2, 3, 4, 4, 4, 4, 4};
    ip[b] = et;
    ip[512 + b] = mp[et];
    x0buf[b * 2 + 0] = hist[b * 4800 + 49 * 6 + 0];
    x0buf[b * 2 + 1] = hist[b * 4800 + 49 * 6 + 1];
  }
  __syncthreads();
  if (b == 0) {
    int cnt[5] = {0, 0, 0, 0, 0};
    for (int i = 0; i < B_; i++) cnt[ip[512 + i]]++;
    int off[6];
    off[0] = 0;
    for (int e = 0; e < 5; e++) off[e + 1] = off[e] + cnt[e];
    int pos[5];
    for (int e = 0; e < 5; e++) pos[e] = off[e];
    for (int i = 0; i < B_; i++) { int e = ip[512 + i]; ip[1024 + pos[e]++] = i; }
    int* tbl = ip + 1536;
    int nrt = 0;
    for (int e = 0; e < 5; e++) {
      int n = cnt[e];
      for (int s = 0; s < n; s += 16) {
        tbl[1 + nrt] = e;
        tbl[37 + nrt] = off[e] + s;
        tbl[73 + nrt] = (n - s) < 16 ? (n - s) : 16;
        nrt++;
      }
    }
    tbl[0] = nrt;
    int* t32 = ip + 1664;
    int n32 = 0;
    for (int e = 0; e < 5; e++) {
      int n = cnt[e];
      for (int s = 0; s < n; s += 32) {
        t32[1 + n32] = e;
        t32[21 + n32] = off[e] + s;
        t32[41 + n32] = (n - s) < 32 ? (n - s) : 32;
        n32++;
      }
    }
    t32[0] = n32;
  }
}

__global__ void k_fill(uint32_t* p, int n, uint32_t v) {
  int i = blockIdx.x * blockDim.x + threadIdx.x;
  if (i < n) p[i] = v;
}

// ---------------- encoder weight pre-pack: lane-major, f64 elements ----------------
// wp[em][cg][k][cl] = {(double)W[k][c], (double)W[k][H+c], (double)W[k][2H+c], 0}
// (double) widening is exact -> downstream math bit-identical to cvt-per-use.
__global__ __launch_bounds__(256) void k_pack(const float* __restrict__ Wih,
                                              const float* __restrict__ Whh,
                                              double4* __restrict__ wp) {
  int i = blockIdx.x * 256 + threadIdx.x;
  if (i >= 20 * 65536) return;
  int cl = i & 31;
  int k  = (i >> 5) & 255;
  int cg = (i >> 13) & 7;
  int em = i >> 16;
  int m = em & 1;
  int el = em >> 1;
  int c = cg * 32 + cl;
  const float* W = (m ? Whh : Wih) + (size_t)el * H_ * TG_;
  double4 v;
  v.x = (double)W[k * TG_ + c];
  v.y = (double)W[k * TG_ + H_ + c];
  v.z = (double)W[k * TG_ + 2 * H_ + c];
  v.w = 0.0;
  wp[i] = v;
}

// ---------------- feature extractor ----------------
__global__ __launch_bounds__(256) void k_feat(const float* __restrict__ hist, const float* __restrict__ emb,
    const float* __restrict__ W1, const float* __restrict__ b1,
    const float* __restrict__ W2, const float* __restrict__ b2,
    const int* __restrict__ ip, float* __restrict__ featbuf) {
  __shared__ float xs[16][22];
  __shared__ float t1[16][H_];
  int row0 = blockIdx.x * 16;
  int tid = threadIdx.x;
  for (int idx = tid; idx < 16 * 22; idx += 256) {
    int r = idx / 22, c = idx % 22;
    int g = row0 + r;
    int b = g / SEQ_, s = g % SEQ_;
    xs[r][c] = (c < 6) ? hist[b * 4800 + s * 6 + c] : emb[ip[b] * EMB_ + (c - 6)];
  }
  __syncthreads();
  int j = tid;
  {
    double acc[16];
    for (int r = 0; r < 16; r++) acc[r] = 0.0;
    for (int k = 0; k < 22; k++) {
      double w = (double)W1[k * H_ + j];
      for (int r = 0; r < 16; r++) acc[r] += (double)xs[r][k] * w;
    }
    double bb = (double)b1[j];
    for (int r = 0; r < 16; r++) t1[r][j] = fmaxf((float)(acc[r] + bb), 0.0f);
  }
  __syncthreads();
  {
    double acc[16];
    for (int r = 0; r < 16; r++) acc[r] = 0.0;
    for (int k = 0; k < H_; k++) {
      double w = (double)W2[k * H_ + j];
      for (int r = 0; r < 16; r++) acc[r] += (double)t1[r][k] * w;
    }
    double bb = (double)b2[j];
    for (int r = 0; r < 16; r++) {
      float v = (float)(acc[r] + bb);
      int g = row0 + r;
      int b = g / SEQ_, s = g % SEQ_;
      featbuf[(size_t)s * (B_ * H_) + (size_t)b * H_ + j] = v;
    }
  }
}

// ---------------- 32-row packed encoder blocks (f64 weights, k-unroll 4) ----------------
// Per-row ascending-k f64 accumulation, same value sequence as r7/r11 -> bit-identical.
__device__ __forceinline__ void gi_block_32(float (*xs)[H_], int* rowb,
    int rt, int cg, int tid,
    const float* __restrict__ x, float* __restrict__ gi_out,
    const double4* __restrict__ wpack, const float* __restrict__ bih_base,
    int layer, const int* __restrict__ ip) {
  const int* t32 = ip + 1664;
  const int* order = ip + 1024;
  int nrt = t32[0];
  if (rt >= nrt) return;
  int e = t32[1 + rt];
  int start = t32[21 + rt];
  int nr = t32[41 + rt];
  for (int idx = tid; idx < 32 * 64; idx += 256) {
    int r = idx >> 6, c4 = idx & 63;
    int rr = (r < nr) ? r : 0;
    int b = order[start + rr];
    if (c4 == 0) rowb[r] = b;
    *(float4*)&xs[r][c4 * 4] = *(const float4*)&x[b * H_ + c4 * 4];
  }
  __syncthreads();
  int j = tid & 31, rs = tid >> 5;   // rows rs, rs+8, rs+16, rs+24
  int c = cg * 32 + j;
  int el = e * NL_ + layer;
  const double4* wp = wpack + (((size_t)(el * 2 + 0) * 8 + cg) * 256) * 32 + j;
  double a[4] = {0, 0, 0, 0}, z[4] = {0, 0, 0, 0}, n[4] = {0, 0, 0, 0};
  for (int k = 0; k < H_; k += 4) {
    double4 w[4];
#pragma unroll
    for (int kk = 0; kk < 4; kk++) w[kk] = wp[(k + kk) * 32];
    float4 xv4[4];
#pragma unroll
    for (int q = 0; q < 4; q++) xv4[q] = *(const float4*)&xs[rs + 8 * q][k];
#pragma unroll
    for (int kk = 0; kk < 4; kk++) {
#pragma unroll
      for (int q = 0; q < 4; q++) {
        double xv = (double)(&xv4[q].x)[kk];
        a[q] += xv * w[kk].x;
        z[q] += xv * w[kk].y;
        n[q] += xv * w[kk].z;
      }
    }
  }
  int cr = c, cz = H_ + c, cn = 2 * H_ + c;
  const float* bih = bih_base + (size_t)el * TG_;
  double br = (double)bih[cr], bz = (double)bih[cz], bn = (double)bih[cn];
#pragma unroll
  for (int q = 0; q < 4; q++) {
    int r = rs + 8 * q;
    if (r >= nr) continue;
    int b = rowb[r];
    gi_out[b * TG_ + cr] = (float)(a[q] + br);
    gi_out[b * TG_ + cz] = (float)(z[q] + bz);
    gi_out[b * TG_ + cn] = (float)(n[q] + bn);
  }
}

__device__ __forceinline__ void step_block_32(float (*hs)[H_], int* rowb,
    int rt, int cg, int tid,
    const float* __restrict__ gi_in, const float* __restrict__ hin,
    float* __restrict__ hout, float* __restrict__ ys,
    const double4* __restrict__ wpack, const float* __restrict__ bhh_base,
    int layer, const int* __restrict__ ip) {
  const int* t32 = ip + 1664;
  const int* order = ip + 1024;
  int nrt = t32[0];
  if (rt >= nrt) return;
  int e = t32[1 + rt];
  int start = t32[21 + rt];
  int nr = t32[41 + rt];
  for (int idx = tid; idx < 32 * 64; idx += 256) {
    int r = idx >> 6, c4 = idx & 63;
    int rr = (r < nr) ? r : 0;
    int b = order[start + rr];
    if (c4 == 0) rowb[r] = b;
    *(float4*)&hs[r][c4 * 4] = *(const float4*)&hin[b * H_ + c4 * 4];
  }
  __syncthreads();
  int j = tid & 31, rs = tid >> 5;
  int c = cg * 32 + j;
  int el = e * NL_ + layer;
  const double4* wp = wpack + (((size_t)(el * 2 + 1) * 8 + cg) * 256) * 32 + j;
  double a[4] = {0, 0, 0, 0}, z[4] = {0, 0, 0, 0}, n[4] = {0, 0, 0, 0};
  for (int k = 0; k < H_; k += 4) {
    double4 w[4];
#pragma unroll
    for (int kk = 0; kk < 4; kk++) w[kk] = wp[(k + kk) * 32];
    float4 hv4[4];
#pragma unroll
    for (int q = 0; q < 4; q++) hv4[q] = *(const float4*)&hs[rs + 8 * q][k];
#pragma unroll
    for (int kk = 0; kk < 4; kk++) {
#pragma unroll
      for (int q = 0; q < 4; q++) {
        double hv = (double)(&hv4[q].x)[kk];
        a[q] += hv * w[kk].x;
        z[q] += hv * w[kk].y;
        n[q] += hv * w[kk].z;
      }
    }
  }
  int cr = c, cz = H_ + c, cn = 2 * H_ + c;
  const float* bhh = bhh_base + (size_t)el * TG_;
  double bhr = (double)bhh[cr], bhz = (double)bhh[cz], bhn = (double)bhh[cn];
#pragma unroll
  for (int q = 0; q < 4; q++) {
    int r = rs + 8 * q;
    if (r >= nr) continue;
    int b = rowb[r];
    double gir = (double)gi_in[b * TG_ + cr];
    double giz = (double)gi_in[b * TG_ + cz];
    double gin = (double)gi_in[b * TG_ + cn];
    double ghr = a[q] + bhr;
    double ghz = z[q] + bhz;
    double ghn = n[q] + bhn;
    double rr = 1.0 / (1.0 + exp(-(gir + ghr)));
    double zz = 1.0 / (1.0 + exp(-(giz + ghz)));
    double nn = tanh(gin + rr * ghn);
    double hv = (double)hs[r][c];
    float hnew = (float)((1.0 - zz) * nn + zz * hv);
    hout[b * H_ + c] = hnew;
    if (ys) ys[b * H_ + c] = hnew;
  }
}

// packed 32-row pipeline dispatch: grid 640 = 4 groups x 20 rt x 8 cg
__global__ __launch_bounds__(256) void k_pipe32(int d,
    const float* __restrict__ feat, float* __restrict__ ys0,
    float* __restrict__ gi0, float* __restrict__ gi1,
    float* __restrict__ h0A, float* __restrict__ h0B,
    float* __restrict__ h1A, float* __restrict__ h1B,
    const double4* __restrict__ wpack,
    const float* __restrict__ bih, const float* __restrict__ bhh,
    const int* __restrict__ ip) {
  __shared__ float sb[32][H_];
  __shared__ int rowb[32];
  int g = blockIdx.x;
  int grp = g / 160, bx = g % 160;
  int rt = bx >> 3, cg = bx & 7;
  int tid = threadIdx.x;
  if (grp == 0) {
    int t = d;
    if (t < SEQ_)
      gi_block_32(sb, rowb, rt, cg, tid, feat + (size_t)t * 131072,
                  gi0 + (size_t)(t & 1) * 393216, wpack, bih, 0, ip);
  } else if (grp == 1) {
    int t = d - 1;
    if (t >= 0 && t < SEQ_) {
      const float* hin = (t & 1) ? h0B : h0A;
      float* hout = (t & 1) ? h0A : h0B;
      step_block_32(sb, rowb, rt, cg, tid, gi0 + (size_t)(t & 1) * 393216,
                    hin, hout, ys0 + (size_t)t * 131072, wpack, bhh, 0, ip);
    }
  } else if (grp == 2) {
    int t = d - 2;
    if (t >= 0 && t < SEQ_)
      gi_block_32(sb, rowb, rt, cg, tid, ys0 + (size_t)t * 131072,
                  gi1 + (size_t)(t & 1) * 393216, wpack, bih, 1, ip);
  } else {
    int t = d - 3;
    if (t >= 0 && t < SEQ_) {
      const float* hin = (t & 1) ? h1B : h1A;
      float* hout = (t & 1) ? h1A : h1B;
      step_block_32(sb, rowb, rt, cg, tid, gi1 + (size_t)(t & 1) * 393216,
                    hin, hout, nullptr, wpack, bhh, 1, ip);
    }
  }
}

// ---- unpacked 16-row fallback (only if ws too small for wpack) ----
__device__ __forceinline__ void gi_block_u(float (*xs)[H_], int* rowb,
    int rt, int cg, int tid,
    const float* __restrict__ x, float* __restrict__ gi_out,
    const float* __restrict__ Wih_base, const float* __restrict__ bih_base,
    int layer, const int* __restrict__ ip) {
  const int* tbl = ip + 1536;
  const int* order = ip + 1024;
  int nrt = tbl[0];
  if (rt >= nrt) return;
  int e = tbl[1 + rt];
  int start = tbl[37 + rt];
  int nr = tbl[73 + rt];
  for (int idx = tid; idx < 16 * H_; idx += 256) {
    int r = idx >> 8, k = idx & 255;
    int rr = (r < nr) ? r : 0;
    int b = order[start + rr];
    if (k == 0) rowb[r] = b;
    xs[r][k] = x[b * H_ + k];
  }
  __syncthreads();
  size_t woff = (size_t)(e * NL_ + layer);
  const float* Wih = Wih_base + woff * (size_t)H_ * TG_;
  const float* bih = bih_base + woff * TG_;
  int j = tid & 31, rs = tid >> 5;
  int c = cg * 32 + j;
  int cr = c, cz = H_ + c, cn = 2 * H_ + c;
  double ar0 = 0, ar1 = 0, az0 = 0, az1 = 0, an0 = 0, an1 = 0;
  for (int k = 0; k < H_; k++) {
    float wr = Wih[k * TG_ + cr], wz = Wih[k * TG_ + cz], wn = Wih[k * TG_ + cn];
    float x0 = xs[rs][k], x1 = xs[rs + 8][k];
    ar0 += (double)x0 * wr; ar1 += (double)x1 * wr;
    az0 += (double)x0 * wz; az1 += (double)x1 * wz;
    an0 += (double)x0 * wn; an1 += (double)x1 * wn;
  }
  double br = (double)bih[cr], bz = (double)bih[cz], bn = (double)bih[cn];
  for (int p = 0; p < 2; p++) {
    int r = rs + 8 * p;
    if (r >= nr) continue;
    int b = rowb[r];
    gi_out[b * TG_ + cr] = (float)((p ? ar1 : ar0) + br);
    gi_out[b * TG_ + cz] = (float)((p ? az1 : az0) + bz);
    gi_out[b * TG_ + cn] = (float)((p ? an1 : an0) + bn);
  }
}

__device__ __forceinline__ void step_block_u(float (*hs)[H_], int* rowb,
    int rt, int cg, int tid,
    const float* __restrict__ gi_in, const float* __restrict__ hin,
    float* __restrict__ hout, float* __restrict__ ys,
    const float* __restrict__ Whh_base, const float* __restrict__ bhh_base,
    int layer, const int* __restrict__ ip) {
  const int* tbl = ip + 1536;
  const int* order = ip + 1024;
  int nrt = tbl[0];
  if (rt >= nrt) return;
  int e = tbl[1 + rt];
  int start = tbl[37 + rt];
  int nr = tbl[73 + rt];
  for (int idx = tid; idx < 16 * H_; idx += 256) {
    int r = idx >> 8, k = idx & 255;
    int rr = (r < nr) ? r : 0;
    int b = order[start + rr];
    if (k == 0) rowb[r] = b;
    hs[r][k] = hin[b * H_ + k];
  }
  __syncthreads();
  size_t woff = (size_t)(e * NL_ + layer);
  const float* Whh = Whh_base + woff * (size_t)H_ * TG_;
  const float* bhh = bhh_base + woff * TG_;
  int j = tid & 31, rs = tid >> 5;
  int c = cg * 32 + j;
  int cr = c, cz = H_ + c, cn = 2 * H_ + c;
  double gr0 = 0, gr1 = 0, gz0 = 0, gz1 = 0, gn0 = 0, gn1 = 0;
  for (int k = 0; k < H_; k++) {
    float wr = Whh[k * TG_ + cr], wz = Whh[k * TG_ + cz], wn = Whh[k * TG_ + cn];
    float h0 = hs[rs][k], h1 = hs[rs + 8][k];
    gr0 += (double)h0 * wr; gr1 += (double)h1 * wr;
    gz0 += (double)h0 * wz; gz1 += (double)h1 * wz;
    gn0 += (double)h0 * wn; gn1 += (double)h1 * wn;
  }
  double bhr = (double)bhh[cr], bhz = (double)bhh[cz], bhn = (double)bhh[cn];
  for (int p = 0; p < 2; p++) {
    int r = rs + 8 * p;
    if (r >= nr) continue;
    int b = rowb[r];
    double gir = (double)gi_in[b * TG_ + cr];
    double giz = (double)gi_in[b * TG_ + cz];
    double gin = (double)gi_in[b * TG_ + cn];
    double ghr = (p ? gr1 : gr0) + bhr;
    double ghz = (p ? gz1 : gz0) + bhz;
    double ghn = (p ? gn1 : gn0) + bhn;
    double rr = 1.0 / (1.0 + exp(-(gir + ghr)));
    double zz = 1.0 / (1.0 + exp(-(giz + ghz)));
    double nn = tanh(gin + rr * ghn);
    double hv = (double)hs[r][c];
    float hnew = (float)((1.0 - zz) * nn + zz * hv);
    hout[b * H_ + c] = hnew;
    if (ys) ys[b * H_ + c] = hnew;
  }
}

__global__ __launch_bounds__(256) void k_pipeu(int d,
    const float* __restrict__ feat, float* __restrict__ ys0,
    float* __restrict__ gi0, float* __restrict__ gi1,
    float* __restrict__ h0A, float* __restrict__ h0B,
    float* __restrict__ h1A, float* __restrict__ h1B,
    const float* __restrict__ Wih, const float* __restrict__ Whh,
    const float* __restrict__ bih, const float* __restrict__ bhh,
    const int* __restrict__ ip) {
  __shared__ float sb[16][H_];
  __shared__ int rowb[16];
  int g = blockIdx.x;
  int grp = g / 288, bx = g % 288;
  int rt = bx >> 3, cg = bx & 7;
  int tid = threadIdx.x;
  if (grp == 0) {
    int t = d; if (t >= SEQ_) return;
    gi_block_u(sb, rowb, rt, cg, tid, feat + (size_t)t * 131072,
               gi0 + (size_t)(t & 1) * 393216, Wih, bih, 0, ip);
  } else if (grp == 1) {
    int t = d - 1; if (t < 0 || t >= SEQ_) return;
    const float* hin = (t & 1) ? h0B : h0A;
    float* hout = (t & 1) ? h0A : h0B;
    step_block_u(sb, rowb, rt, cg, tid, gi0 + (size_t)(t & 1) * 393216,
                 hin, hout, ys0 + (size_t)t * 131072, Whh, bhh, 0, ip);
  } else if (grp == 2) {
    int t = d - 2; if (t < 0 || t >= SEQ_) return;
    gi_block_u(sb, rowb, rt, cg, tid, ys0 + (size_t)t * 131072,
               gi1 + (size_t)(t & 1) * 393216, Wih, bih, 1, ip);
  } else {
    int t = d - 3; if (t < 0 || t >= SEQ_) return;
    const float* hin = (t & 1) ? h1B : h1A;
    float* hout = (t & 1) ? h1A : h1B;
    step_block_u(sb, rowb, rt, cg, tid, gi1 + (size_t)(t & 1) * 393216,
                 hin, hout, nullptr, Whh, bhh, 1, ip);
  }
}

// ---------------- decoder GRU ----------------
template <int D1>
__global__ __launch_bounds__(256) void k_gru(
    const float* __restrict__ x, const float* __restrict__ hin,
    float* __restrict__ hout,
    const float* __restrict__ Wih, const float* __restrict__ Whh,
    const float* __restrict__ bih, const float* __restrict__ bhh) {
  __shared__ float xs[16][(D1 == 2) ? 2 : H_];
  __shared__ float hs[16][H_];
  int bx = blockIdx.x, by = blockIdx.y;
  int start = bx * 16;
  int tid = threadIdx.x;
  for (int idx = tid; idx < 16 * H_; idx += 256) {
    int r = idx >> 8, k = idx & 255;
    int b = start + r;
    hs[r][k] = hin[b * H_ + k];
    if (D1 == H_) xs[r][k] = x[b * H_ + k];
    else if (k < D1) xs[r][k] = x[b * D1 + k];
  }
  __syncthreads();
  int j = tid & 31, rs = tid >> 5;
  int hc = by * 32 + j;
  int cr = hc, cz = H_ + hc, cn = 2 * H_ + hc;
  double ra0 = 0, ra1 = 0, za0 = 0, za1 = 0, ni0 = 0, ni1 = 0, nh0 = 0, nh1 = 0;
  for (int k = 0; k < H_; k++) {
    float wrh = Whh[k * TG_ + cr], wzh = Whh[k * TG_ + cz], wnh = Whh[k * TG_ + cn];
    float h0v = hs[rs][k], h1v = hs[rs + 8][k];
    ra0 += (double)h0v * wrh; ra1 += (double)h1v * wrh;
    za0 += (double)h0v * wzh; za1 += (double)h1v * wzh;
    nh0 += (double)h0v * wnh; nh1 += (double)h1v * wnh;
    if (D1 == H_) {
      float wri = Wih[k * TG_ + cr], wzi = Wih[k * TG_ + cz], wni = Wih[k * TG_ + cn];
      float x0v = xs[rs][k], x1v = xs[rs + 8][k];
      ra0 += (double)x0v * wri; ra1 += (double)x1v * wri;
      za0 += (double)x0v * wzi; za1 += (double)x1v * wzi;
      ni0 += (double)x0v * wni; ni1 += (double)x1v * wni;
    }
  }
  if (D1 != H_) {
    for (int k = 0; k < D1; k++) {
      float wri = Wih[k * TG_ + cr], wzi = Wih[k * TG_ + cz], wni = Wih[k * TG_ + cn];
      float x0v = xs[rs][k], x1v = xs[rs + 8][k];
      ra0 += (double)x0v * wri; ra1 += (double)x1v * wri;
      za0 += (double)x0v * wzi; za1 += (double)x1v * wzi;
      ni0 += (double)x0v * wni; ni1 += (double)x1v * wni;
    }
  }
  double br_i = (double)bih[cr], bz_i = (double)bih[cz], bn_i = (double)bih[cn];
  double br_h = (double)bhh[cr], bz_h = (double)bhh[cz], bn_h = (double)bhh[cn];
  for (int p = 0; p < 2; p++) {
    int r = rs + 8 * p;
    double ra = p ? ra1 : ra0, za = p ? za1 : za0, ni = p ? ni1 : ni0, nh = p ? nh1 : nh0;
    double rr = 1.0 / (1.0 + exp(-(ra + br_i + br_h)));
    double zz = 1.0 / (1.0 + exp(-(za + bz_i + bz_h)));
    double nn = tanh((ni + bn_i) + rr * (nh + bn_h));
    double hv = (double)hs[r][hc];
    float hnew = (float)((1.0 - zz) * nn + zz * hv);
    hout[(start + r) * H_ + hc] = hnew;
  }
}

// ---------------- heads ----------------
__global__ __launch_bounds__(256) void k_heads(const float* __restrict__ lh,
    const float* __restrict__ hgW1, const float* __restrict__ hgb1,
    const float* __restrict__ hgW2, const float* __restrict__ hgb2,
    const float* __restrict__ hgW3, const float* __restrict__ hgb3,
    const float* __restrict__ ceW1, const float* __restrict__ ceb1,
    const float* __restrict__ ceW2, const float* __restrict__ ceb2,
    float* __restrict__ out) {
  __shared__ float hsm[16][H_];
  __shared__ float t1[16][H_];
  __shared__ float t2[16][H2_];
  __shared__ float c2s[16][T_];
  int row0 = blockIdx.x * 16;
  int tid = threadIdx.x;
  for (int idx = tid; idx < 16 * H_; idx += 256) {
    int r = idx >> 8, k = idx & 255;
    hsm[r][k] = lh[(size_t)(row0 + r) * H_ + k];
  }
  __syncthreads();
  {
    int j = tid;
    for (int r = 0; r < 16; r++) {
      double a = 0;
      for (int k = 0; k < H_; k++) a += (double)hsm[r][k] * (double)hgW1[k * H_ + j];
      t1[r][j] = fmaxf((float)(a + (double)hgb1[j]), 0.0f);
    }
  }
  __syncthreads();
  if (tid < H2_) {
    int j = tid;
    for (int r = 0; r < 16; r++) {
      double a = 0;
      for (int k = 0; k < H_; k++) a += (double)t1[r][k] * (double)hgW2[k * H2_ + j];
      t2[r][j] = fmaxf((float)(a + (double)hgb2[j]), 0.0f);
    }
  }
  __syncthreads();
  if (tid < 2 * T_) {
    int j = tid;
    for (int r = 0; r < 16; r++) {
      double a = 0;
      for (int k = 0; k < H2_; k++) a += (double)t2[r][k] * (double)hgW3[k * (2 * T_) + j];
      float v = (float)(a + (double)hgb3[j]);
      int b = row0 + r;
      int t = j >> 1, c = j & 1;
      out[(((size_t)b * S_ + 0) * T_ + t) * 2 + c] = v;
    }
  }
  __syncthreads();
  if (tid < H2_) {
    int j = tid;
    for (int r = 0; r < 16; r++) {
      double a = 0;
      for (int k = 0; k < H_; k++) a += (double)hsm[r][k] * (double)ceW1[k * H2_ + j];
      t2[r][j] = fmaxf((float)(a + (double)ceb1[j]), 0.0f);
    }
  }
  __syncthreads();
  if (tid < T_) {
    int j = tid;
    for (int r = 0; r < 16; r++) {
      double a = 0;
      for (int k = 0; k < H2_; k++) a += (double)t2[r][k] * (double)ceW2[k * T_ + j];
      c2s[r][j] = (float)(a + (double)ceb2[j]);
    }
  }
  __syncthreads();
  if (tid < 16) {
    int r = tid;
    int b = row0 + r;
    double s = 0;
    for (int j = 0; j < T_; j++) s += (double)c2s[r][j];
    float m = (float)(s / 60.0);
    for (int sd = 0; sd < S_; sd++) {
      float d = (float)pow((double)0.9f, (double)sd);
      out[368640 + b * S_ + sd] = __fmul_rn(m, d);
    }
  }
}

// ---------------- hp layer1 ----------------
__global__ __launch_bounds__(256) void k_hp1(const float* __restrict__ lh,
    const float* __restrict__ W1, const float* __restrict__ b1,
    float* __restrict__ h1buf, uint32_t nk0, uint32_t nk1) {
  __shared__ float th[16][H_];
  int row0 = blockIdx.x * 16;
  int tid = threadIdx.x;
  const float SQRT2F = 1.4142135623730951f;
  const float LO = -0x1.fffffep-1f;
  for (int idx = tid; idx < 16 * H_; idx += 256) {
    int r = idx >> 8, k = idx & 255;
    int g = row0 + r;
    int t = g / B_, b = g % B_;
    uint32_t i = ((uint32_t)t * B_ + (uint32_t)b) * H_ + (uint32_t)k;
    uint32_t bits = jax_bits(nk0, nk1, i, NOISE_N);
    float f = bits_to_f01(bits);
    float u = fmaxf(LO, __fadd_rn(__fmul_rn(f, 2.0f), LO));
    float nz = __fmul_rn(SQRT2F, erfinv_f(u));
    float sc = __fdiv_rn(__fmul_rn(0.1f, (float)t), 60.0f);
    th[r][k] = __fadd_rn(lh[(size_t)b * H_ + k], __fmul_rn(nz, sc));
  }
  __syncthreads();
  int j = tid;
  double acc[16];
  for (int r = 0; r < 16; r++) acc[r] = 0.0;
  for (int k = 0; k < H_; k++) {
    double w = (double)W1[k * H_ + j];
    for (int r = 0; r < 16; r++) acc[r] += (double)th[r][k] * w;
  }
  double bb = (double)b1[j];
  for (int r = 0; r < 16; r++)
    h1buf[(size_t)(row0 + r) * H_ + j] = fmaxf((float)(acc[r] + bb), 0.0f);
}

// ---------------- hp layer2 + gumbel-argmin transform ----------------
// argmax_c(logit_c + (-log(-log u_c)))  ==  argmin_c((-log u_c) * exp(-logit_c))
// (exact-arithmetic identity; f32 rounding differs ~1-2ulp -> flip risk ~0.06 expected).
// Cross-block combine: atomicMin on (orderkey(w)<<32 | cat); equal keys -> lowest cat
// wins (JAX first-index). samples initialized to ~0ULL.
__global__ __launch_bounds__(256) void k_hp2(const float* __restrict__ h1buf,
    const float* __restrict__ W2, const float* __restrict__ b2,
    unsigned long long* __restrict__ samples, uint32_t sk0, uint32_t sk1) {
  __shared__ float h1[16][H_];
  int row0 = blockIdx.x * 16;
  int cat0 = blockIdx.y * 256;
  int tid = threadIdx.x;
  for (int idx = tid; idx < 16 * H_ / 4; idx += 256) {
    int r = idx >> 6, k4 = (idx & 63) << 2;
    *(float4*)&h1[r][k4] = *(const float4*)&h1buf[(size_t)(row0 + r) * H_ + k4];
  }
  __syncthreads();
  int wave = tid >> 6;
  int lane = tid & 63;
  int catA = cat0 + 4 * lane;
  int rbase = 4 * wave;

  f32x2 acc[4][2];
#pragma unroll
  for (int r = 0; r < 4; r++) { acc[r][0] = (f32x2)0.0f; acc[r][1] = (f32x2)0.0f; }
  const float* w2p = W2 + catA;
  for (int k = 0; k < H_; k += 4) {
    float4 hv[4];
    hv[0] = *(const float4*)&h1[rbase + 0][k];
    hv[1] = *(const float4*)&h1[rbase + 1][k];
    hv[2] = *(const float4*)&h1[rbase + 2][k];
    hv[3] = *(const float4*)&h1[rbase + 3][k];
    float4 wv[4];
#pragma unroll
    for (int kk = 0; kk < 4; kk++) wv[kk] = *(const float4*)&w2p[(size_t)(k + kk) * CAT_];
#pragma unroll
    for (int kk = 0; kk < 4; kk++) {
      f32x2 wlo; wlo.x = wv[kk].x; wlo.y = wv[kk].y;
      f32x2 whi; whi.x = wv[kk].z; whi.y = wv[kk].w;
#pragma unroll
      for (int r = 0; r < 4; r++) {
        f32x2 hp;
        if (kk & 2) { hp.x = (&hv[r].x)[2]; hp.y = (&hv[r].x)[3]; }
        else        { hp.x = (&hv[r].x)[0]; hp.y = (&hv[r].x)[1]; }
        if (kk & 1) { PKFMA_HI(acc[r][0], wlo, hp); PKFMA_HI(acc[r][1], whi, hp); }
        else        { PKFMA_LO(acc[r][0], wlo, hp); PKFMA_LO(acc[r][1], whi, hp); }
      }
    }
  }
  // el = exp(-logit), hoisted once per lane (16 expf, reused across 20 (s,q) iters)
  float el[4][4];
  float4 b4 = *(const float4*)&b2[catA];
#pragma unroll
  for (int r = 0; r < 4; r++) {
    el[r][0] = expf(-__fadd_rn(acc[r][0].x, b4.x));
    el[r][1] = expf(-__fadd_rn(acc[r][0].y, b4.y));
    el[r][2] = expf(-__fadd_rn(acc[r][1].x, b4.z));
    el[r][3] = expf(-__fadd_rn(acc[r][1].y, b4.w));
  }

  const float FMIN = 1.17549435e-38f;
  int t = row0 / B_;
  int bbase = row0 % B_;
#pragma unroll
  for (int s = 0; s < S_ - 1; s++) {
#pragma unroll
    for (int q = 0; q < 4; q++) {
      int brow = bbase + rbase + q;
      uint32_t ibase = (((uint32_t)s * T_ + (uint32_t)t) * B_ + (uint32_t)brow) * CAT_ + (uint32_t)catA;
      float w0, w1, w2, w3;
      {
        float u0 = fmaxf(bits_to_f01(jax_bits(sk0, sk1, ibase + 0u, GUMBEL_N)), FMIN);
        float u1 = fmaxf(bits_to_f01(jax_bits(sk0, sk1, ibase + 1u, GUMBEL_N)), FMIN);
        float u2 = fmaxf(bits_to_f01(jax_bits(sk0, sk1, ibase + 2u, GUMBEL_N)), FMIN);
        float u3 = fmaxf(bits_to_f01(jax_bits(sk0, sk1, ibase + 3u, GUMBEL_N)), FMIN);
        w0 = __fmul_rn(-logf(u0), el[q][0]);
        w1 = __fmul_rn(-logf(u1), el[q][1]);
        w2 = __fmul_rn(-logf(u2), el[q][2]);
        w3 = __fmul_rn(-logf(u3), el[q][3]);
      }
      // local argmin, strict < keeps lowest cat on ties (JAX first-index)
      float bs = w0; int bc = catA;
      if (w1 < bs) { bs = w1; bc = catA + 1; }
      if (w2 < bs) { bs = w2; bc = catA + 2; }
      if (w3 < bs) { bs = w3; bc = catA + 3; }
      float mv = bs;
      for (int off = 1; off < 64; off <<= 1)
        mv = fminf(mv, __shfl_xor(mv, off, 64));
      unsigned long long mask = __ballot(bs == mv);
      int src = __ffsll(mask) - 1;               // lowest lane = lowest cat
      int wcat = __shfl(bc, src, 64);
      if (lane == 0) {
        unsigned long long p =
            (((unsigned long long)orderkey(mv)) << 32) | (unsigned long long)(uint32_t)wcat;
        atomicMin(&samples[((size_t)s * T_ + t) * B_ + brow], p);
      }
    }
  }
}

// ---------------- decode samples -> grid points (min-key packing: cat in low bits) ----------------
__global__ void k_emit(const unsigned long long* __restrict__ samples, float* __restrict__ out) {
  int gid = blockIdx.x * blockDim.x + threadIdx.x;
  if (gid >= (S_ - 1) * T_ * B_) return;
  int b = gid % B_;
  int t = (gid / B_) % T_;
  int s = gid / (B_ * T_);
  unsigned long long v = samples[gid];
  uint32_t cat = (uint32_t)(v & 0xFFFFFFFFu);
  float xi = (float)(cat & 63u);
  float yi = (float)(cat >> 6);
  float px = -50.0f + xi * 1.5625f + 0.78125f;
  float py = -50.0f + yi * 1.5625f + 0.78125f;
  size_t o = (((size_t)b * S_ + (size_t)(s + 1)) * T_ + t) * 2;
  out[o] = px;
  out[o + 1] = py;
}

// ---------------- host ----------------
extern "C" void kernel_launch(void* const* d_in, const int* in_sizes, int n_in,
                              void* d_out, int out_size, void* d_ws, size_t ws_size,
                              hipStream_t stream) {
  (void)in_sizes; (void)n_in; (void)out_size;
  const float* hist   = (const float*)d_in[0];
  const float* emb    = (const float*)d_in[1];
  const float* feW1   = (const float*)d_in[2];
  const float* feb1   = (const float*)d_in[3];
  const float* feW2   = (const float*)d_in[4];
  const float* feb2   = (const float*)d_in[5];
  const float* encWih = (const float*)d_in[6];
  const float* encWhh = (const float*)d_in[7];
  const float* encbih = (const float*)d_in[8];
  const float* encbhh = (const float*)d_in[9];
  const float* dWih0  = (const float*)d_in[10];
  const float* dWhh0  = (const float*)d_in[11];
  const float* dbih0  = (const float*)d_in[12];
  const float* dbhh0  = (const float*)d_in[13];
  const float* dWih1  = (const float*)d_in[14];
  const float* dWhh1  = (const float*)d_in[15];
  const float* dbih1  = (const float*)d_in[16];
  const float* dbhh1  = (const float*)d_in[17];
  const float* hgW1   = (const float*)d_in[18];
  const float* hgb1   = (const float*)d_in[19];
  const float* hgW2   = (const float*)d_in[20];
  const float* hgb2   = (const float*)d_in[21];
  const float* hgW3   = (const float*)d_in[22];
  const float* hgb3   = (const float*)d_in[23];
  const float* ceW1   = (const float*)d_in[24];
  const float* ceb1   = (const float*)d_in[25];
  const float* ceW2   = (const float*)d_in[26];
  const float* ceb2   = (const float*)d_in[27];
  const float* hpW1   = (const float*)d_in[28];
  const float* hpb1   = (const float*)d_in[29];
  const float* hpW2   = (const float*)d_in[30];
  const float* hpb2   = (const float*)d_in[31];
  float* out = (float*)d_out;
  float* ws = (float*)d_ws;

  float* feat  = ws;
  float* ys0   = ws + 6553600;
  float* gi0   = ws + 13107200;
  float* gi1   = ws + 13893632;
  float* h0A   = ws + 14680064;
  float* h0B   = h0A + 131072;
  float* h1A   = h0B + 131072;
  float* h1B   = h1A + 131072;
  float* dech0 = h1B + 131072;
  float* lh    = dech0 + 131072;
  float* x0buf = lh + 131072;
  int*   ip    = (int*)(x0buf + 1024);
  unsigned long long* samples =
      (unsigned long long*)(((uintptr_t)(ip + 2048) + 255) & ~(uintptr_t)255);
  float* h1hp  = ws;   // alias: feat+ys0 head, dead after encoder

  size_t samples_end = (size_t)((char*)(samples + 307200) - (char*)ws);
  size_t wpack_off = (samples_end + 255) & ~(size_t)255;
  double4* wpack = (double4*)((char*)ws + wpack_off);
  bool packed = (wpack_off + (size_t)20 * 65536 * 32) <= ws_size;

  uint32_t kn0, kn1, ks0, ks1;
#if JAX_PARTITIONABLE
  tf2x32(0u, 42u, 0u, 0u, kn0, kn1);
  tf2x32(0u, 42u, 0u, 1u, ks0, ks1);
#else
  { uint32_t a0, a1, b0, b1;
    tf2x32(0u, 42u, 0u, 2u, a0, a1);
    tf2x32(0u, 42u, 1u, 3u, b0, b1);
    kn0 = a0; kn1 = b0; ks0 = a1; ks1 = b1; }
#endif

  k_init<<<dim3(1), dim3(512), 0, stream>>>(hist, x0buf, ip);
  k_fill<<<dim3((524288 + 255) / 256), dim3(256), 0, stream>>>((uint32_t*)h0A, 524288, 0u);
  k_fill<<<dim3((307200 + 255) / 256), dim3(256), 0, stream>>>((uint32_t*)samples, 307200, 0xFFFFFFFFu);
  if (packed)
    k_pack<<<dim3(5120), dim3(256), 0, stream>>>(encWih, encWhh, wpack);
  k_feat<<<dim3(1600), dim3(256), 0, stream>>>(hist, emb, feW1, feb1, feW2, feb2, ip, feat);

  if (packed) {
    for (int d = 0; d < SEQ_ + 3; d++)
      k_pipe32<<<dim3(640), dim3(256), 0, stream>>>(d,
          feat, ys0, gi0, gi1, h0A, h0B, h1A, h1B,
          wpack, encbih, encbhh, ip);
  } else {
    for (int d = 0; d < SEQ_ + 3; d++)
      k_pipeu<<<dim3(1152), dim3(256), 0, stream>>>(d,
          feat, ys0, gi0, gi1, h0A, h0B, h1A, h1B,
          encWih, encWhh, encbih, encbhh, ip);
  }

  k_gru<2><<<dim3(32, 8), dim3(256), 0, stream>>>(
      x0buf, h0A, dech0, dWih0, dWhh0, dbih0, dbhh0);
  k_gru<H_><<<dim3(32, 8), dim3(256), 0, stream>>>(
      dech0, h1A, lh, dWih1, dWhh1, dbih1, dbhh1);

  k_heads<<<dim3(32), dim3(256), 0, stream>>>(lh, hgW1, hgb1, hgW2, hgb2, hgW3, hgb3,
                                              ceW1, ceb1, ceW2, ceb2, out);
  k_hp1<<<dim3(1920), dim3(256), 0, stream>>>(lh, hpW1, hpb1, h1hp, kn0, kn1);
  k_hp2<<<dim3(1920, 16), dim3(256), 0, stream>>>(h1hp, hpW2, hpb2, samples, ks0, ks1);
  k_emit<<<dim3(600), dim3(256), 0, stream>>>(samples, out);
}

// Round 13
// 5356.907 us; speedup vs baseline: 1.1556x; 1.1556x over previous
//
#include <hip/hip_runtime.h>
#include <stdint.h>
#include <math.h>

#define JAX_PARTITIONABLE 1

#define B_ 512
#define SEQ_ 50
#define H_ 256
#define H2_ 128
#define T_ 60
#define S_ 6
#define EMB_ 16
#define NL_ 2
#define TG_ 768     // 3*H
#define CAT_ 4096   // G*G
#define GUMBEL_N 629145600u  // (S-1)*T*B*CAT
#define NOISE_N 7864320u     // T*B*H

typedef float f32x2 __attribute__((ext_vector_type(2)));

// packed fp32 FMA, h broadcast via op_sel on src1 (bit-exact IEEE f32 FMA)
#define PKFMA_LO(acc, w, h) \
  asm("v_pk_fma_f32 %0, %1, %2, %0 op_sel:[0,0,0] op_sel_hi:[1,0,1]" : "+v"(acc) : "v"(w), "v"(h))
#define PKFMA_HI(acc, w, h) \
  asm("v_pk_fma_f32 %0, %1, %2, %0 op_sel:[0,1,0] op_sel_hi:[1,1,1]" : "+v"(acc) : "v"(w), "v"(h))

__host__ __device__ inline uint32_t rotl32(uint32_t x, int r) {
#if defined(__HIP_DEVICE_COMPILE__)
  return __builtin_amdgcn_alignbit(x, x, 32 - r);
#else
  return (x << r) | (x >> (32 - r));
#endif
}

// ---------------- Threefry-2x32 (20 rounds), matches jax._src.prng ----------------
__host__ __device__ inline void tf2x32(uint32_t k0, uint32_t k1, uint32_t x0, uint32_t x1,
                                       uint32_t& o0, uint32_t& o1) {
  uint32_t ks2 = k0 ^ k1 ^ 0x1BD11BDAu;
  x0 += k0; x1 += k1;
#define TFR(r) do { x0 += x1; x1 = rotl32(x1, r); x1 ^= x0; } while (0)
  TFR(13); TFR(15); TFR(26); TFR(6);
  x0 += k1; x1 += ks2 + 1u;
  TFR(17); TFR(29); TFR(16); TFR(24);
  x0 += ks2; x1 += k0 + 2u;
  TFR(13); TFR(15); TFR(26); TFR(6);
  x0 += k0; x1 += k1 + 3u;
  TFR(17); TFR(29); TFR(16); TFR(24);
  x0 += k1; x1 += ks2 + 4u;
  TFR(13); TFR(15); TFR(26); TFR(6);
  x0 += ks2; x1 += k0 + 5u;
#undef TFR
  o0 = x0; o1 = x1;
}

__device__ inline uint32_t jax_bits(uint32_t k0, uint32_t k1, uint32_t i, uint32_t n) {
#if JAX_PARTITIONABLE
  (void)n;
  uint32_t a, b;
  tf2x32(k0, k1, 0u, i, a, b);
  return a ^ b;
#else
  uint32_t half = n >> 1;
  uint32_t lo = (i < half) ? i : (i - half);
  uint32_t a, b;
  tf2x32(k0, k1, lo, lo + half, a, b);
  return (i < half) ? a : b;
#endif
}

__device__ inline float bits_to_f01(uint32_t bits) {
  return __uint_as_float((bits >> 9) | 0x3f800000u) - 1.0f;
}

// erf_inv, CHLO/Giles f32 polynomial; w from double log
__device__ inline float erfinv_f(float x) {
  double xd = (double)x;
  float w = (float)(-log((1.0 - xd) * (1.0 + xd)));
  float p;
  if (w < 5.0f) {
    w = __fadd_rn(w, -2.5f);
    p = 2.81022636e-08f;
    p = __fadd_rn(3.43273939e-07f, __fmul_rn(p, w));
    p = __fadd_rn(-3.5233877e-06f, __fmul_rn(p, w));
    p = __fadd_rn(-4.39150654e-06f, __fmul_rn(p, w));
    p = __fadd_rn(0.00021858087f, __fmul_rn(p, w));
    p = __fadd_rn(-0.00125372503f, __fmul_rn(p, w));
    p = __fadd_rn(-0.00417768164f, __fmul_rn(p, w));
    p = __fadd_rn(0.246640727f, __fmul_rn(p, w));
    p = __fadd_rn(1.50140941f, __fmul_rn(p, w));
  } else {
    w = __fadd_rn(__fsqrt_rn(w), -3.0f);
    p = -0.000200214257f;
    p = __fadd_rn(0.000100950558f, __fmul_rn(p, w));
    p = __fadd_rn(0.00134934322f, __fmul_rn(p, w));
    p = __fadd_rn(-0.00367342844f, __fmul_rn(p, w));
    p = __fadd_rn(0.00573950773f, __fmul_rn(p, w));
    p = __fadd_rn(-0.0076224613f, __fmul_rn(p, w));
    p = __fadd_rn(0.00943887047f, __fmul_rn(p, w));
    p = __fadd_rn(1.00167406f, __fmul_rn(p, w));
    p = __fadd_rn(2.83297682f, __fmul_rn(p, w));
  }
  return __fmul_rn(p, x);
}

__device__ inline uint32_t orderkey(float s) {
  uint32_t sb = __float_as_uint(s);
  return (sb & 0x80000000u) ? ~sb : (sb | 0x80000000u);
}

// ---------------- init ----------------
__global__ __launch_bounds__(512) void k_init(const float* __restrict__ hist,
                                              float* __restrict__ x0buf, int* __restrict__ ip) {
  int b = threadIdx.x;
  if (b < B_) {
    float tv = hist[b * 4800 + 5];
    int et = (int)tv;
    et = et < 0 ? 0 : (et > 9 ? 9 : et);
    const int mp[10] = {0, 1, 4, 2, 3, 4, 4, 4, 4, 4};
    ip[b] = et;
    ip[512 + b] = mp[et];
    x0buf[b * 2 + 0] = hist[b * 4800 + 49 * 6 + 0];
    x0buf[b * 2 + 1] = hist[b * 4800 + 49 * 6 + 1];
  }
  __syncthreads();
  if (b == 0) {
    int cnt[5] = {0, 0, 0, 0, 0};
    for (int i = 0; i < B_; i++) cnt[ip[512 + i]]++;
    int off[6];
    off[0] = 0;
    for (int e = 0; e < 5; e++) off[e + 1] = off[e] + cnt[e];
    int pos[5];
    for (int e = 0; e < 5; e++) pos[e] = off[e];
    for (int i = 0; i < B_; i++) { int e = ip[512 + i]; ip[1024 + pos[e]++] = i; }
    int* tbl = ip + 1536;
    int nrt = 0;
    for (int e = 0; e < 5; e++) {
      int n = cnt[e];
      for (int s = 0; s < n; s += 16) {
        tbl[1 + nrt] = e;
        tbl[37 + nrt] = off[e] + s;
        tbl[73 + nrt] = (n - s) < 16 ? (n - s) : 16;
        nrt++;
      }
    }
    tbl[0] = nrt;
    int* t32 = ip + 1664;
    int n32 = 0;
    for (int e = 0; e < 5; e++) {
      int n = cnt[e];
      for (int s = 0; s < n; s += 32) {
        t32[1 + n32] = e;
        t32[21 + n32] = off[e] + s;
        t32[41 + n32] = (n - s) < 32 ? (n - s) : 32;
        n32++;
      }
    }
    t32[0] = n32;
  }
}

__global__ void k_fill(uint32_t* p, int n, uint32_t v) {
  int i = blockIdx.x * blockDim.x + threadIdx.x;
  if (i < n) p[i] = v;
}

// ---------------- encoder weight pre-pack (lane-major f32, r7/r11-validated) ----------------
__global__ __launch_bounds__(256) void k_pack(const float* __restrict__ Wih,
                                              const float* __restrict__ Whh,
                                              float4* __restrict__ wp) {
  int i = blockIdx.x * 256 + threadIdx.x;
  if (i >= 20 * 65536) return;
  int cl = i & 31;
  int k  = (i >> 5) & 255;
  int cg = (i >> 13) & 7;
  int em = i >> 16;
  int m = em & 1;
  int el = em >> 1;
  int c = cg * 32 + cl;
  const float* W = (m ? Whh : Wih) + (size_t)el * H_ * TG_;
  float4 v;
  v.x = W[k * TG_ + c];
  v.y = W[k * TG_ + H_ + c];
  v.z = W[k * TG_ + 2 * H_ + c];
  v.w = 0.0f;
  wp[i] = v;
}

// ---------------- feature extractor ----------------
__global__ __launch_bounds__(256) void k_feat(const float* __restrict__ hist, const float* __restrict__ emb,
    const float* __restrict__ W1, const float* __restrict__ b1,
    const float* __restrict__ W2, const float* __restrict__ b2,
    const int* __restrict__ ip, float* __restrict__ featbuf) {
  __shared__ float xs[16][22];
  __shared__ float t1[16][H_];
  int row0 = blockIdx.x * 16;
  int tid = threadIdx.x;
  for (int idx = tid; idx < 16 * 22; idx += 256) {
    int r = idx / 22, c = idx % 22;
    int g = row0 + r;
    int b = g / SEQ_, s = g % SEQ_;
    xs[r][c] = (c < 6) ? hist[b * 4800 + s * 6 + c] : emb[ip[b] * EMB_ + (c - 6)];
  }
  __syncthreads();
  int j = tid;
  {
    double acc[16];
    for (int r = 0; r < 16; r++) acc[r] = 0.0;
    for (int k = 0; k < 22; k++) {
      double w = (double)W1[k * H_ + j];
      for (int r = 0; r < 16; r++) acc[r] += (double)xs[r][k] * w;
    }
    double bb = (double)b1[j];
    for (int r = 0; r < 16; r++) t1[r][j] = fmaxf((float)(acc[r] + bb), 0.0f);
  }
  __syncthreads();
  {
    double acc[16];
    for (int r = 0; r < 16; r++) acc[r] = 0.0;
    for (int k = 0; k < H_; k++) {
      double w = (double)W2[k * H_ + j];
      for (int r = 0; r < 16; r++) acc[r] += (double)t1[r][k] * w;
    }
    double bb = (double)b2[j];
    for (int r = 0; r < 16; r++) {
      float v = (float)(acc[r] + bb);
      int g = row0 + r;
      int b = g / SEQ_, s = g % SEQ_;
      featbuf[(size_t)s * (B_ * H_) + (size_t)b * H_ + j] = v;
    }
  }
}

// ---------------- 32-row packed encoder blocks (f32 weights, k-unroll 8; r11-validated) ----------------
__device__ __forceinline__ void gi_block_32(float (*xs)[H_], int* rowb,
    int rt, int cg, int tid,
    const float* __restrict__ x, float* __restrict__ gi_out,
    const float4* __restrict__ wpack, const float* __restrict__ bih_base,
    int layer, const int* __restrict__ ip) {
  const int* t32 = ip + 1664;
  const int* order = ip + 1024;
  int nrt = t32[0];
  if (rt >= nrt) return;
  int e = t32[1 + rt];
  int start = t32[21 + rt];
  int nr = t32[41 + rt];
  for (int idx = tid; idx < 32 * 64; idx += 256) {
    int r = idx >> 6, c4 = idx & 63;
    int rr = (r < nr) ? r : 0;
    int b = order[start + rr];
    if (c4 == 0) rowb[r] = b;
    *(float4*)&xs[r][c4 * 4] = *(const float4*)&x[b * H_ + c4 * 4];
  }
  __syncthreads();
  int j = tid & 31, rs = tid >> 5;   // rows rs, rs+8, rs+16, rs+24
  int c = cg * 32 + j;
  int el = e * NL_ + layer;
  const float4* wp = wpack + (((size_t)(el * 2 + 0) * 8 + cg) * 256) * 32 + j;
  double a[4] = {0, 0, 0, 0}, z[4] = {0, 0, 0, 0}, n[4] = {0, 0, 0, 0};
  for (int k = 0; k < H_; k += 8) {
    float4 w[8];
#pragma unroll
    for (int kk = 0; kk < 8; kk++) w[kk] = wp[(k + kk) * 32];
    float4 xlo[4], xhi[4];
#pragma unroll
    for (int q = 0; q < 4; q++) {
      xlo[q] = *(const float4*)&xs[rs + 8 * q][k];
      xhi[q] = *(const float4*)&xs[rs + 8 * q][k + 4];
    }
#pragma unroll
    for (int kk = 0; kk < 8; kk++) {
#pragma unroll
      for (int q = 0; q < 4; q++) {
        float xv = (kk < 4) ? (&xlo[q].x)[kk] : (&xhi[q].x)[kk - 4];
        a[q] += (double)xv * (double)w[kk].x;
        z[q] += (double)xv * (double)w[kk].y;
        n[q] += (double)xv * (double)w[kk].z;
      }
    }
  }
  int cr = c, cz = H_ + c, cn = 2 * H_ + c;
  const float* bih = bih_base + (size_t)el * TG_;
  double br = (double)bih[cr], bz = (double)bih[cz], bn = (double)bih[cn];
#pragma unroll
  for (int q = 0; q < 4; q++) {
    int r = rs + 8 * q;
    if (r >= nr) continue;
    int b = rowb[r];
    gi_out[b * TG_ + cr] = (float)(a[q] + br);
    gi_out[b * TG_ + cz] = (float)(z[q] + bz);
    gi_out[b * TG_ + cn] = (float)(n[q] + bn);
  }
}

__device__ __forceinline__ void step_block_32(float (*hs)[H_], int* rowb,
    int rt, int cg, int tid,
    const float* __restrict__ gi_in, const float* __restrict__ hin,
    float* __restrict__ hout, float* __restrict__ ys,
    const float4* __restrict__ wpack, const float* __restrict__ bhh_base,
    int layer, const int* __restrict__ ip) {
  const int* t32 = ip + 1664;
  const int* order = ip + 1024;
  int nrt = t32[0];
  if (rt >= nrt) return;
  int e = t32[1 + rt];
  int start = t32[21 + rt];
  int nr = t32[41 + rt];
  for (int idx = tid; idx < 32 * 64; idx += 256) {
    int r = idx >> 6, c4 = idx & 63;
    int rr = (r < nr) ? r : 0;
    int b = order[start + rr];
    if (c4 == 0) rowb[r] = b;
    *(float4*)&hs[r][c4 * 4] = *(const float4*)&hin[b * H_ + c4 * 4];
  }
  __syncthreads();
  int j = tid & 31, rs = tid >> 5;
  int c = cg * 32 + j;
  int el = e * NL_ + layer;
  const float4* wp = wpack + (((size_t)(el * 2 + 1) * 8 + cg) * 256) * 32 + j;
  double a[4] = {0, 0, 0, 0}, z[4] = {0, 0, 0, 0}, n[4] = {0, 0, 0, 0};
  for (int k = 0; k < H_; k += 8) {
    float4 w[8];
#pragma unroll
    for (int kk = 0; kk < 8; kk++) w[kk] = wp[(k + kk) * 32];
    float4 hlo[4], hhi[4];
#pragma unroll
    for (int q = 0; q < 4; q++) {
      hlo[q] = *(const float4*)&hs[rs + 8 * q][k];
      hhi[q] = *(const float4*)&hs[rs + 8 * q][k + 4];
    }
#pragma unroll
    for (int kk = 0; kk < 8; kk++) {
#pragma unroll
      for (int q = 0; q < 4; q++) {
        float hv = (kk < 4) ? (&hlo[q].x)[kk] : (&hhi[q].x)[kk - 4];
        a[q] += (double)hv * (double)w[kk].x;
        z[q] += (double)hv * (double)w[kk].y;
        n[q] += (double)hv * (double)w[kk].z;
      }
    }
  }
  int cr = c, cz = H_ + c, cn = 2 * H_ + c;
  const float* bhh = bhh_base + (size_t)el * TG_;
  double bhr = (double)bhh[cr], bhz = (double)bhh[cz], bhn = (double)bhh[cn];
#pragma unroll
  for (int q = 0; q < 4; q++) {
    int r = rs + 8 * q;
    if (r >= nr) continue;
    int b = rowb[r];
    double gir = (double)gi_in[b * TG_ + cr];
    double giz = (double)gi_in[b * TG_ + cz];
    double gin = (double)gi_in[b * TG_ + cn];
    double ghr = a[q] + bhr;
    double ghz = z[q] + bhz;
    double ghn = n[q] + bhn;
    double rr = 1.0 / (1.0 + exp(-(gir + ghr)));
    double zz = 1.0 / (1.0 + exp(-(giz + ghz)));
    double nn = tanh(gin + rr * ghn);
    double hv = (double)hs[r][c];
    float hnew = (float)((1.0 - zz) * nn + zz * hv);
    hout[b * H_ + c] = hnew;
    if (ys) ys[b * H_ + c] = hnew;
  }
}

// packed 32-row pipeline dispatch: grid 640 = 4 groups x 20 rt x 8 cg
__global__ __launch_bounds__(256) void k_pipe32(int d,
    const float* __restrict__ feat, float* __restrict__ ys0,
    float* __restrict__ gi0, float* __restrict__ gi1,
    float* __restrict__ h0A, float* __restrict__ h0B,
    float* __restrict__ h1A, float* __restrict__ h1B,
    const float4* __restrict__ wpack,
    const float* __restrict__ bih, const float* __restrict__ bhh,
    const int* __restrict__ ip) {
  __shared__ float sb[32][H_];
  __shared__ int rowb[32];
  int g = blockIdx.x;
  int grp = g / 160, bx = g % 160;
  int rt = bx >> 3, cg = bx & 7;
  int tid = threadIdx.x;
  if (grp == 0) {
    int t = d;
    if (t < SEQ_)
      gi_block_32(sb, rowb, rt, cg, tid, feat + (size_t)t * 131072,
                  gi0 + (size_t)(t & 1) * 393216, wpack, bih, 0, ip);
  } else if (grp == 1) {
    int t = d - 1;
    if (t >= 0 && t < SEQ_) {
      const float* hin = (t & 1) ? h0B : h0A;
      float* hout = (t & 1) ? h0A : h0B;
      step_block_32(sb, rowb, rt, cg, tid, gi0 + (size_t)(t & 1) * 393216,
                    hin, hout, ys0 + (size_t)t * 131072, wpack, bhh, 0, ip);
    }
  } else if (grp == 2) {
    int t = d - 2;
    if (t >= 0 && t < SEQ_)
      gi_block_32(sb, rowb, rt, cg, tid, ys0 + (size_t)t * 131072,
                  gi1 + (size_t)(t & 1) * 393216, wpack, bih, 1, ip);
  } else {
    int t = d - 3;
    if (t >= 0 && t < SEQ_) {
      const float* hin = (t & 1) ? h1B : h1A;
      float* hout = (t & 1) ? h1A : h1B;
      step_block_32(sb, rowb, rt, cg, tid, gi1 + (size_t)(t & 1) * 393216,
                    hin, hout, nullptr, wpack, bhh, 1, ip);
    }
  }
}

// ---- unpacked 16-row fallback (only if ws too small for wpack) ----
__device__ __forceinline__ void gi_block_u(float (*xs)[H_], int* rowb,
    int rt, int cg, int tid,
    const float* __restrict__ x, float* __restrict__ gi_out,
    const float* __restrict__ Wih_base, const float* __restrict__ bih_base,
    int layer, const int* __restrict__ ip) {
  const int* tbl = ip + 1536;
  const int* order = ip + 1024;
  int nrt = tbl[0];
  if (rt >= nrt) return;
  int e = tbl[1 + rt];
  int start = tbl[37 + rt];
  int nr = tbl[73 + rt];
  for (int idx = tid; idx < 16 * H_; idx += 256) {
    int r = idx >> 8, k = idx & 255;
    int rr = (r < nr) ? r : 0;
    int b = order[start + rr];
    if (k == 0) rowb[r] = b;
    xs[r][k] = x[b * H_ + k];
  }
  __syncthreads();
  size_t woff = (size_t)(e * NL_ + layer);
  const float* Wih = Wih_base + woff * (size_t)H_ * TG_;
  const float* bih = bih_base + woff * TG_;
  int j = tid & 31, rs = tid >> 5;
  int c = cg * 32 + j;
  int cr = c, cz = H_ + c, cn = 2 * H_ + c;
  double ar0 = 0, ar1 = 0, az0 = 0, az1 = 0, an0 = 0, an1 = 0;
  for (int k = 0; k < H_; k++) {
    float wr = Wih[k * TG_ + cr], wz = Wih[k * TG_ + cz], wn = Wih[k * TG_ + cn];
    float x0 = xs[rs][k], x1 = xs[rs + 8][k];
    ar0 += (double)x0 * wr; ar1 += (double)x1 * wr;
    az0 += (double)x0 * wz; az1 += (double)x1 * wz;
    an0 += (double)x0 * wn; an1 += (double)x1 * wn;
  }
  double br = (double)bih[cr], bz = (double)bih[cz], bn = (double)bih[cn];
  for (int p = 0; p < 2; p++) {
    int r = rs + 8 * p;
    if (r >= nr) continue;
    int b = rowb[r];
    gi_out[b * TG_ + cr] = (float)((p ? ar1 : ar0) + br);
    gi_out[b * TG_ + cz] = (float)((p ? az1 : az0) + bz);
    gi_out[b * TG_ + cn] = (float)((p ? an1 : an0) + bn);
  }
}

__device__ __forceinline__ void step_block_u(float (*hs)[H_], int* rowb,
    int rt, int cg, int tid,
    const float* __restrict__ gi_in, const float* __restrict__ hin,
    float* __restrict__ hout, float* __restrict__ ys,
    const float* __restrict__ Whh_base, const float* __restrict__ bhh_base,
    int layer, const int* __restrict__ ip) {
  const int* tbl = ip + 1536;
  const int* order = ip + 1024;
  int nrt = tbl[0];
  if (rt >= nrt) return;
  int e = tbl[1 + rt];
  int start = tbl[37 + rt];
  int nr = tbl[73 + rt];
  for (int idx = tid; idx < 16 * H_; idx += 256) {
    int r = idx >> 8, k = idx & 255;
    int rr = (r < nr) ? r : 0;
    int b = order[start + rr];
    if (k == 0) rowb[r] = b;
    hs[r][k] = hin[b * H_ + k];
  }
  __syncthreads();
  size_t woff = (size_t)(e * NL_ + layer);
  const float* Whh = Whh_base + woff * (size_t)H_ * TG_;
  const float* bhh = bhh_base + woff * TG_;
  int j = tid & 31, rs = tid >> 5;
  int c = cg * 32 + j;
  int cr = c, cz = H_ + c, cn = 2 * H_ + c;
  double gr0 = 0, gr1 = 0, gz0 = 0, gz1 = 0, gn0 = 0, gn1 = 0;
  for (int k = 0; k < H_; k++) {
    float wr = Whh[k * TG_ + cr], wz = Whh[k * TG_ + cz], wn = Whh[k * TG_ + cn];
    float h0 = hs[rs][k], h1 = hs[rs + 8][k];
    gr0 += (double)h0 * wr; gr1 += (double)h1 * wr;
    gz0 += (double)h0 * wz; gz1 += (double)h1 * wz;
    gn0 += (double)h0 * wn; gn1 += (double)h1 * wn;
  }
  double bhr = (double)bhh[cr], bhz = (double)bhh[cz], bhn = (double)bhh[cn];
  for (int p = 0; p < 2; p++) {
    int r = rs + 8 * p;
    if (r >= nr) continue;
    int b = rowb[r];
    double gir = (double)gi_in[b * TG_ + cr];
    double giz = (double)gi_in[b * TG_ + cz];
    double gin = (double)gi_in[b * TG_ + cn];
    double ghr = (p ? gr1 : gr0) + bhr;
    double ghz = (p ? gz1 : gz0) + bhz;
    double ghn = (p ? gn1 : gn0) + bhn;
    double rr = 1.0 / (1.0 + exp(-(gir + ghr)));
    double zz = 1.0 / (1.0 + exp(-(giz + ghz)));
    double nn = tanh(gin + rr * ghn);
    double hv = (double)hs[r][c];
    float hnew = (float)((1.0 - zz) * nn + zz * hv);
    hout[b * H_ + c] = hnew;
    if (ys) ys[b * H_ + c] = hnew;
  }
}

__global__ __launch_bounds__(256) void k_pipeu(int d,
    const float* __restrict__ feat, float* __restrict__ ys0,
    float* __restrict__ gi0, float* __restrict__ gi1,
    float* __restrict__ h0A, float* __restrict__ h0B,
    float* __restrict__ h1A, float* __restrict__ h1B,
    const float* __restrict__ Wih, const float* __restrict__ Whh,
    const float* __restrict__ bih, const float* __restrict__ bhh,
    const int* __restrict__ ip) {
  __shared__ float sb[16][H_];
  __shared__ int rowb[16];
  int g = blockIdx.x;
  int grp = g / 288, bx = g % 288;
  int rt = bx >> 3, cg = bx & 7;
  int tid = threadIdx.x;
  if (grp == 0) {
    int t = d; if (t >= SEQ_) return;
    gi_block_u(sb, rowb, rt, cg, tid, feat + (size_t)t * 131072,
               gi0 + (size_t)(t & 1) * 393216, Wih, bih, 0, ip);
  } else if (grp == 1) {
    int t = d - 1; if (t < 0 || t >= SEQ_) return;
    const float* hin = (t & 1) ? h0B : h0A;
    float* hout = (t & 1) ? h0A : h0B;
    step_block_u(sb, rowb, rt, cg, tid, gi0 + (size_t)(t & 1) * 393216,
                 hin, hout, ys0 + (size_t)t * 131072, Whh, bhh, 0, ip);
  } else if (grp == 2) {
    int t = d - 2; if (t < 0 || t >= SEQ_) return;
    gi_block_u(sb, rowb, rt, cg, tid, ys0 + (size_t)t * 131072,
               gi1 + (size_t)(t & 1) * 393216, Wih, bih, 1, ip);
  } else {
    int t = d - 3; if (t < 0 || t >= SEQ_) return;
    const float* hin = (t & 1) ? h1B : h1A;
    float* hout = (t & 1) ? h1A : h1B;
    step_block_u(sb, rowb, rt, cg, tid, gi1 + (size_t)(t & 1) * 393216,
                 hin, hout, nullptr, Whh, bhh, 1, ip);
  }
}

// ---------------- decoder GRU ----------------
template <int D1>
__global__ __launch_bounds__(256) void k_gru(
    const float* __restrict__ x, const float* __restrict__ hin,
    float* __restrict__ hout,
    const float* __restrict__ Wih, const float* __restrict__ Whh,
    const float* __restrict__ bih, const float* __restrict__ bhh) {
  __shared__ float xs[16][(D1 == 2) ? 2 : H_];
  __shared__ float hs[16][H_];
  int bx = blockIdx.x, by = blockIdx.y;
  int start = bx * 16;
  int tid = threadIdx.x;
  for (int idx = tid; idx < 16 * H_; idx += 256) {
    int r = idx >> 8, k = idx & 255;
    int b = start + r;
    hs[r][k] = hin[b * H_ + k];
    if (D1 == H_) xs[r][k] = x[b * H_ + k];
    else if (k < D1) xs[r][k] = x[b * D1 + k];
  }
  __syncthreads();
  int j = tid & 31, rs = tid >> 5;
  int hc = by * 32 + j;
  int cr = hc, cz = H_ + hc, cn = 2 * H_ + hc;
  double ra0 = 0, ra1 = 0, za0 = 0, za1 = 0, ni0 = 0, ni1 = 0, nh0 = 0, nh1 = 0;
  for (int k = 0; k < H_; k++) {
    float wrh = Whh[k * TG_ + cr], wzh = Whh[k * TG_ + cz], wnh = Whh[k * TG_ + cn];
    float h0v = hs[rs][k], h1v = hs[rs + 8][k];
    ra0 += (double)h0v * wrh; ra1 += (double)h1v * wrh;
    za0 += (double)h0v * wzh; za1 += (double)h1v * wzh;
    nh0 += (double)h0v * wnh; nh1 += (double)h1v * wnh;
    if (D1 == H_) {
      float wri = Wih[k * TG_ + cr], wzi = Wih[k * TG_ + cz], wni = Wih[k * TG_ + cn];
      float x0v = xs[rs][k], x1v = xs[rs + 8][k];
      ra0 += (double)x0v * wri; ra1 += (double)x1v * wri;
      za0 += (double)x0v * wzi; za1 += (double)x1v * wzi;
      ni0 += (double)x0v * wni; ni1 += (double)x1v * wni;
    }
  }
  if (D1 != H_) {
    for (int k = 0; k < D1; k++) {
      float wri = Wih[k * TG_ + cr], wzi = Wih[k * TG_ + cz], wni = Wih[k * TG_ + cn];
      float x0v = xs[rs][k], x1v = xs[rs + 8][k];
      ra0 += (double)x0v * wri; ra1 += (double)x1v * wri;
      za0 += (double)x0v * wzi; za1 += (double)x1v * wzi;
      ni0 += (double)x0v * wni; ni1 += (double)x1v * wni;
    }
  }
  double br_i = (double)bih[cr], bz_i = (double)bih[cz], bn_i = (double)bih[cn];
  double br_h = (double)bhh[cr], bz_h = (double)bhh[cz], bn_h = (double)bhh[cn];
  for (int p = 0; p < 2; p++) {
    int r = rs + 8 * p;
    double ra = p ? ra1 : ra0, za = p ? za1 : za0, ni = p ? ni1 : ni0, nh = p ? nh1 : nh0;
    double rr = 1.0 / (1.0 + exp(-(ra + br_i + br_h)));
    double zz = 1.0 / (1.0 + exp(-(za + bz_i + bz_h)));
    double nn = tanh((ni + bn_i) + rr * (nh + bn_h));
    double hv = (double)hs[r][hc];
    float hnew = (float)((1.0 - zz) * nn + zz * hv);
    hout[(start + r) * H_ + hc] = hnew;
  }
}

// ---------------- heads ----------------
__global__ __launch_bounds__(256) void k_heads(const float* __restrict__ lh,
    const float* __restrict__ hgW1, const float* __restrict__ hgb1,
    const float* __restrict__ hgW2, const float* __restrict__ hgb2,
    const float* __restrict__ hgW3, const float* __restrict__ hgb3,
    const float* __restrict__ ceW1, const float* __restrict__ ceb1,
    const float* __restrict__ ceW2, const float* __restrict__ ceb2,
    float* __restrict__ out) {
  __shared__ float hsm[16][H_];
  __shared__ float t1[16][H_];
  __shared__ float t2[16][H2_];
  __shared__ float c2s[16][T_];
  int row0 = blockIdx.x * 16;
  int tid = threadIdx.x;
  for (int idx = tid; idx < 16 * H_; idx += 256) {
    int r = idx >> 8, k = idx & 255;
    hsm[r][k] = lh[(size_t)(row0 + r) * H_ + k];
  }
  __syncthreads();
  {
    int j = tid;
    for (int r = 0; r < 16; r++) {
      double a = 0;
      for (int k = 0; k < H_; k++) a += (double)hsm[r][k] * (double)hgW1[k * H_ + j];
      t1[r][j] = fmaxf((float)(a + (double)hgb1[j]), 0.0f);
    }
  }
  __syncthreads();
  if (tid < H2_) {
    int j = tid;
    for (int r = 0; r < 16; r++) {
      double a = 0;
      for (int k = 0; k < H_; k++) a += (double)t1[r][k] * (double)hgW2[k * H2_ + j];
      t2[r][j] = fmaxf((float)(a + (double)hgb2[j]), 0.0f);
    }
  }
  __syncthreads();
  if (tid < 2 * T_) {
    int j = tid;
    for (int r = 0; r < 16; r++) {
      double a = 0;
      for (int k = 0; k < H2_; k++) a += (double)t2[r][k] * (double)hgW3[k * (2 * T_) + j];
      float v = (float)(a + (double)hgb3[j]);
      int b = row0 + r;
      int t = j >> 1, c = j & 1;
      out[(((size_t)b * S_ + 0) * T_ + t) * 2 + c] = v;
    }
  }
  __syncthreads();
  if (tid < H2_) {
    int j = tid;
    for (int r = 0; r < 16; r++) {
      double a = 0;
      for (int k = 0; k < H_; k++) a += (double)hsm[r][k] * (double)ceW1[k * H2_ + j];
      t2[r][j] = fmaxf((float)(a + (double)ceb1[j]), 0.0f);
    }
  }
  __syncthreads();
  if (tid < T_) {
    int j = tid;
    for (int r = 0; r < 16; r++) {
      double a = 0;
      for (int k = 0; k < H2_; k++) a += (double)t2[r][k] * (double)ceW2[k * T_ + j];
      c2s[r][j] = (float)(a + (double)ceb2[j]);
    }
  }
  __syncthreads();
  if (tid < 16) {
    int r = tid;
    int b = row0 + r;
    double s = 0;
    for (int j = 0; j < T_; j++) s += (double)c2s[r][j];
    float m = (float)(s / 60.0);
    for (int sd = 0; sd < S_; sd++) {
      float d = (float)pow((double)0.9f, (double)sd);
      out[368640 + b * S_ + sd] = __fmul_rn(m, d);
    }
  }
}

// ---------------- hp layer1 ----------------
__global__ __launch_bounds__(256) void k_hp1(const float* __restrict__ lh,
    const float* __restrict__ W1, const float* __restrict__ b1,
    float* __restrict__ h1buf, uint32_t nk0, uint32_t nk1) {
  __shared__ float th[16][H_];
  int row0 = blockIdx.x * 16;
  int tid = threadIdx.x;
  const float SQRT2F = 1.4142135623730951f;
  const float LO = -0x1.fffffep-1f;
  for (int idx = tid; idx < 16 * H_; idx += 256) {
    int r = idx >> 8, k = idx & 255;
    int g = row0 + r;
    int t = g / B_, b = g % B_;
    uint32_t i = ((uint32_t)t * B_ + (uint32_t)b) * H_ + (uint32_t)k;
    uint32_t bits = jax_bits(nk0, nk1, i, NOISE_N);
    float f = bits_to_f01(bits);
    float u = fmaxf(LO, __fadd_rn(__fmul_rn(f, 2.0f), LO));
    float nz = __fmul_rn(SQRT2F, erfinv_f(u));
    float sc = __fdiv_rn(__fmul_rn(0.1f, (float)t), 60.0f);
    th[r][k] = __fadd_rn(lh[(size_t)b * H_ + k], __fmul_rn(nz, sc));
  }
  __syncthreads();
  int j = tid;
  double acc[16];
  for (int r = 0; r < 16; r++) acc[r] = 0.0;
  for (int k = 0; k < H_; k++) {
    double w = (double)W1[k * H_ + j];
    for (int r = 0; r < 16; r++) acc[r] += (double)th[r][k] * w;
  }
  double bb = (double)b1[j];
  for (int r = 0; r < 16; r++)
    h1buf[(size_t)(row0 + r) * H_ + j] = fmaxf((float)(acc[r] + bb), 0.0f);
}

// ---------------- hp layer2 + gumbel-argmin transform (r12-validated) ----------------
// argmax_c(logit_c + (-log(-log u_c)))  ==  argmin_c((-log u_c) * exp(-logit_c)).
// Cross-block combine: atomicMin on (orderkey(w)<<32 | cat); samples init 0xFF..
__global__ __launch_bounds__(256) void k_hp2(const float* __restrict__ h1buf,
    const float* __restrict__ W2, const float* __restrict__ b2,
    unsigned long long* __restrict__ samples, uint32_t sk0, uint32_t sk1) {
  __shared__ float h1[16][H_];
  int row0 = blockIdx.x * 16;
  int cat0 = blockIdx.y * 256;
  int tid = threadIdx.x;
  for (int idx = tid; idx < 16 * H_ / 4; idx += 256) {
    int r = idx >> 6, k4 = (idx & 63) << 2;
    *(float4*)&h1[r][k4] = *(const float4*)&h1buf[(size_t)(row0 + r) * H_ + k4];
  }
  __syncthreads();
  int wave = tid >> 6;
  int lane = tid & 63;
  int catA = cat0 + 4 * lane;
  int rbase = 4 * wave;

  f32x2 acc[4][2];
#pragma unroll
  for (int r = 0; r < 4; r++) { acc[r][0] = (f32x2)0.0f; acc[r][1] = (f32x2)0.0f; }
  const float* w2p = W2 + catA;
  for (int k = 0; k < H_; k += 4) {
    float4 hv[4];
    hv[0] = *(const float4*)&h1[rbase + 0][k];
    hv[1] = *(const float4*)&h1[rbase + 1][k];
    hv[2] = *(const float4*)&h1[rbase + 2][k];
    hv[3] = *(const float4*)&h1[rbase + 3][k];
    float4 wv[4];
#pragma unroll
    for (int kk = 0; kk < 4; kk++) wv[kk] = *(const float4*)&w2p[(size_t)(k + kk) * CAT_];
#pragma unroll
    for (int kk = 0; kk < 4; kk++) {
      f32x2 wlo; wlo.x = wv[kk].x; wlo.y = wv[kk].y;
      f32x2 whi; whi.x = wv[kk].z; whi.y = wv[kk].w;
#pragma unroll
      for (int r = 0; r < 4; r++) {
        f32x2 hp;
        if (kk & 2) { hp.x = (&hv[r].x)[2]; hp.y = (&hv[r].x)[3]; }
        else        { hp.x = (&hv[r].x)[0]; hp.y = (&hv[r].x)[1]; }
        if (kk & 1) { PKFMA_HI(acc[r][0], wlo, hp); PKFMA_HI(acc[r][1], whi, hp); }
        else        { PKFMA_LO(acc[r][0], wlo, hp); PKFMA_LO(acc[r][1], whi, hp); }
      }
    }
  }
  // el = exp(-logit), hoisted once per lane (16 expf, reused across 20 (s,q) iters)
  float el[4][4];
  float4 b4 = *(const float4*)&b2[catA];
#pragma unroll
  for (int r = 0; r < 4; r++) {
    el[r][0] = expf(-__fadd_rn(acc[r][0].x, b4.x));
    el[r][1] = expf(-__fadd_rn(acc[r][0].y, b4.y));
    el[r][2] = expf(-__fadd_rn(acc[r][1].x, b4.z));
    el[r][3] = expf(-__fadd_rn(acc[r][1].y, b4.w));
  }

  const float FMIN = 1.17549435e-38f;
  int t = row0 / B_;
  int bbase = row0 % B_;
#pragma unroll
  for (int s = 0; s < S_ - 1; s++) {
#pragma unroll
    for (int q = 0; q < 4; q++) {
      int brow = bbase + rbase + q;
      uint32_t ibase = (((uint32_t)s * T_ + (uint32_t)t) * B_ + (uint32_t)brow) * CAT_ + (uint32_t)catA;
      float w0, w1, w2, w3;
      {
        float u0 = fmaxf(bits_to_f01(jax_bits(sk0, sk1, ibase + 0u, GUMBEL_N)), FMIN);
        float u1 = fmaxf(bits_to_f01(jax_bits(sk0, sk1, ibase + 1u, GUMBEL_N)), FMIN);
        float u2 = fmaxf(bits_to_f01(jax_bits(sk0, sk1, ibase + 2u, GUMBEL_N)), FMIN);
        float u3 = fmaxf(bits_to_f01(jax_bits(sk0, sk1, ibase + 3u, GUMBEL_N)), FMIN);
        w0 = __fmul_rn(-logf(u0), el[q][0]);
        w1 = __fmul_rn(-logf(u1), el[q][1]);
        w2 = __fmul_rn(-logf(u2), el[q][2]);
        w3 = __fmul_rn(-logf(u3), el[q][3]);
      }
      float bs = w0; int bc = catA;
      if (w1 < bs) { bs = w1; bc = catA + 1; }
      if (w2 < bs) { bs = w2; bc = catA + 2; }
      if (w3 < bs) { bs = w3; bc = catA + 3; }
      float mv = bs;
      for (int off = 1; off < 64; off <<= 1)
        mv = fminf(mv, __shfl_xor(mv, off, 64));
      unsigned long long mask = __ballot(bs == mv);
      int src = __ffsll(mask) - 1;               // lowest lane = lowest cat
      int wcat = __shfl(bc, src, 64);
      if (lane == 0) {
        unsigned long long p =
            (((unsigned long long)orderkey(mv)) << 32) | (unsigned long long)(uint32_t)wcat;
        atomicMin(&samples[((size_t)s * T_ + t) * B_ + brow], p);
      }
    }
  }
}

// ---------------- decode samples -> grid points (min-key packing: cat in low bits) ----------------
__global__ void k_emit(const unsigned long long* __restrict__ samples, float* __restrict__ out) {
  int gid = blockIdx.x * blockDim.x + threadIdx.x;
  if (gid >= (S_ - 1) * T_ * B_) return;
  int b = gid % B_;
  int t = (gid / B_) % T_;
  int s = gid / (B_ * T_);
  unsigned long long v = samples[gid];
  uint32_t cat = (uint32_t)(v & 0xFFFFFFFFu);
  float xi = (float)(cat & 63u);
  float yi = (float)(cat >> 6);
  float px = -50.0f + xi * 1.5625f + 0.78125f;
  float py = -50.0f + yi * 1.5625f + 0.78125f;
  size_t o = (((size_t)b * S_ + (size_t)(s + 1)) * T_ + t) * 2;
  out[o] = px;
  out[o + 1] = py;
}

// ---------------- host ----------------
extern "C" void kernel_launch(void* const* d_in, const int* in_sizes, int n_in,
                              void* d_out, int out_size, void* d_ws, size_t ws_size,
                              hipStream_t stream) {
  (void)in_sizes; (void)n_in; (void)out_size;
  const float* hist   = (const float*)d_in[0];
  const float* emb    = (const float*)d_in[1];
  const float* feW1   = (const float*)d_in[2];
  const float* feb1   = (const float*)d_in[3];
  const float* feW2   = (const float*)d_in[4];
  const float* feb2   = (const float*)d_in[5];
  const float* encWih = (const float*)d_in[6];
  const float* encWhh = (const float*)d_in[7];
  const float* encbih = (const float*)d_in[8];
  const float* encbhh = (const float*)d_in[9];
  const float* dWih0  = (const float*)d_in[10];
  const float* dWhh0  = (const float*)d_in[11];
  const float* dbih0  = (const float*)d_in[12];
  const float* dbhh0  = (const float*)d_in[13];
  const float* dWih1  = (const float*)d_in[14];
  const float* dWhh1  = (const float*)d_in[15];
  const float* dbih1  = (const float*)d_in[16];
  const float* dbhh1  = (const float*)d_in[17];
  const float* hgW1   = (const float*)d_in[18];
  const float* hgb1   = (const float*)d_in[19];
  const float* hgW2   = (const float*)d_in[20];
  const float* hgb2   = (const float*)d_in[21];
  const float* hgW3   = (const float*)d_in[22];
  const float* hgb3   = (const float*)d_in[23];
  const float* ceW1   = (const float*)d_in[24];
  const float* ceb1   = (const float*)d_in[25];
  const float* ceW2   = (const float*)d_in[26];
  const float* ceb2   = (const float*)d_in[27];
  const float* hpW1   = (const float*)d_in[28];
  const float* hpb1   = (const float*)d_in[29];
  const float* hpW2   = (const float*)d_in[30];
  const float* hpb2   = (const float*)d_in[31];
  float* out = (float*)d_out;
  float* ws = (float*)d_ws;

  float* feat  = ws;
  float* ys0   = ws + 6553600;
  float* gi0   = ws + 13107200;
  float* gi1   = ws + 13893632;
  float* h0A   = ws + 14680064;
  float* h0B   = h0A + 131072;
  float* h1A   = h0B + 131072;
  float* h1B   = h1A + 131072;
  float* dech0 = h1B + 131072;
  float* lh    = dech0 + 131072;
  float* x0buf = lh + 131072;
  int*   ip    = (int*)(x0buf + 1024);
  unsigned long long* samples =
      (unsigned long long*)(((uintptr_t)(ip + 2048) + 255) & ~(uintptr_t)255);
  float* h1hp  = ws;   // alias: feat+ys0 head, dead after encoder

  size_t samples_end = (size_t)((char*)(samples + 307200) - (char*)ws);
  size_t wpack_off = (samples_end + 255) & ~(size_t)255;
  float4* wpack = (float4*)((char*)ws + wpack_off);
  bool packed = (wpack_off + (size_t)20 * 65536 * 16) <= ws_size;

  uint32_t kn0, kn1, ks0, ks1;
#if JAX_PARTITIONABLE
  tf2x32(0u, 42u, 0u, 0u, kn0, kn1);
  tf2x32(0u, 42u, 0u, 1u, ks0, ks1);
#else
  { uint32_t a0, a1, b0, b1;
    tf2x32(0u, 42u, 0u, 2u, a0, a1);
    tf2x32(0u, 42u, 1u, 3u, b0, b1);
    kn0 = a0; kn1 = b0; ks0 = a1; ks1 = b1; }
#endif

  k_init<<<dim3(1), dim3(512), 0, stream>>>(hist, x0buf, ip);
  k_fill<<<dim3((524288 + 255) / 256), dim3(256), 0, stream>>>((uint32_t*)h0A, 524288, 0u);
  k_fill<<<dim3((307200 + 255) / 256), dim3(256), 0, stream>>>((uint32_t*)samples, 307200, 0xFFFFFFFFu);
  if (packed)
    k_pack<<<dim3(5120), dim3(256), 0, stream>>>(encWih, encWhh, wpack);
  k_feat<<<dim3(1600), dim3(256), 0, stream>>>(hist, emb, feW1, feb1, feW2, feb2, ip, feat);

  if (packed) {
    for (int d = 0; d < SEQ_ + 3; d++)
      k_pipe32<<<dim3(640), dim3(256), 0, stream>>>(d,
          feat, ys0, gi0, gi1, h0A, h0B, h1A, h1B,
          wpack, encbih, encbhh, ip);
  } else {
    for (int d = 0; d < SEQ_ + 3; d++)
      k_pipeu<<<dim3(1152), dim3(256), 0, stream>>>(d,
          feat, ys0, gi0, gi1, h0A, h0B, h1A, h1B,
          encWih, encWhh, encbih, encbhh, ip);
  }

  k_gru<2><<<dim3(32, 8), dim3(256), 0, stream>>>(
      x0buf, h0A, dech0, dWih0, dWhh0, dbih0, dbhh0);
  k_gru<H_><<<dim3(32, 8), dim3(256), 0, stream>>>(
      dech0, h1A, lh, dWih1, dWhh1, dbih1, dbhh1);

  k_heads<<<dim3(32), dim3(256), 0, stream>>>(lh, hgW1, hgb1, hgW2, hgb2, hgW3, hgb3,
                                              ceW1, ceb1, ceW2, ceb2, out);
  k_hp1<<<dim3(1920), dim3(256), 0, stream>>>(lh, hpW1, hpb1, h1hp, kn0, kn1);
  k_hp2<<<dim3(1920, 16), dim3(256), 0, stream>>>(h1hp, hpW2, hpb2, samples, ks0, ks1);
  k_emit<<<dim3(600), dim3(256), 0, stream>>>(samples, out);
}